// Round 3
// baseline (1404.718 us; speedup 1.0000x reference)
//
#include <hip/hip_runtime.h>
#include <cstdint>
#include <cstddef>

#define LSEQ 2048
#define NB 16
#define NROWS (NB*LSEQ)   // 32768

typedef __attribute__((ext_vector_type(8))) __bf16 bf16x8;
typedef __attribute__((ext_vector_type(4))) float f32x4;
typedef unsigned short u16;
typedef unsigned int u32;

__device__ __forceinline__ u16 f2bf(float f) {
    u32 u = __float_as_uint(f);
    return (u16)((u + 0x7FFFu + ((u >> 16) & 1u)) >> 16);  // RNE
}
__device__ __forceinline__ float bf2f(u16 h) {
    return __uint_as_float(((u32)h) << 16);
}
__device__ __forceinline__ void gl_lds16(const u16* g, u16* l) {
    __builtin_amdgcn_global_load_lds(
        (const __attribute__((address_space(1))) u32*)g,
        (__attribute__((address_space(3))) u32*)l, 16, 0, 0);
}
// sum over the 16-lane DPP row (s-groups are lane&15 -> exactly one DPP row slice)
__device__ __forceinline__ float row_reduce16(float x) {
    int t;
    t = __builtin_amdgcn_update_dpp(0, __float_as_int(x), 0x128, 0xF, 0xF, true); // row_ror:8
    x += __int_as_float(t);
    t = __builtin_amdgcn_update_dpp(0, __float_as_int(x), 0x124, 0xF, 0xF, true); // row_ror:4
    x += __int_as_float(t);
    t = __builtin_amdgcn_update_dpp(0, __float_as_int(x), 0x122, 0xF, 0xF, true); // row_ror:2
    x += __int_as_float(t);
    t = __builtin_amdgcn_update_dpp(0, __float_as_int(x), 0x121, 0xF, 0xF, true); // row_ror:1
    x += __int_as_float(t);
    return x;
}

// ---------- fp32 -> bf16 weight convert ----------
__global__ void k_tobf16(const float* __restrict__ in, u16* __restrict__ out, int n) {
    int i = blockIdx.x * 256 + threadIdx.x;
    if (i < n) out[i] = f2bf(in[i]);
}

// ---------- h = seq @ inp_w^T + inp_b  (32768x64 @ 64x256) ----------
__global__ __launch_bounds__(256) void k_embed(const float* __restrict__ seq,
        const float* __restrict__ w, const float* __restrict__ b, float* __restrict__ h) {
    __shared__ float s[8][64];
    int r0 = blockIdx.x * 8;
    int tid = threadIdx.x;
    for (int i = tid; i < 512; i += 256)
        s[i >> 6][i & 63] = seq[(size_t)(r0 + (i >> 6)) * 64 + (i & 63)];
    __syncthreads();
    float acc[8] = {0,0,0,0,0,0,0,0};
    #pragma unroll
    for (int k4 = 0; k4 < 64; k4 += 4) {
        float4 wv = *(const float4*)&w[(size_t)tid * 64 + k4];
        #pragma unroll
        for (int r = 0; r < 8; r++)
            acc[r] += s[r][k4]*wv.x + s[r][k4+1]*wv.y + s[r][k4+2]*wv.z + s[r][k4+3]*wv.w;
    }
    float bias = b[tid];
    #pragma unroll
    for (int r = 0; r < 8; r++)
        h[(size_t)(r0 + r) * 256 + tid] = acc[r] + bias;
}

// ---------- layernorm over 256; one wave per row ----------
template<bool BFOUT>
__global__ __launch_bounds__(256) void k_ln(const float* __restrict__ h,
        const float* __restrict__ lw, const float* __restrict__ lb, void* __restrict__ outp) {
    int row = blockIdx.x * 4 + (threadIdx.x >> 6);
    int lane = threadIdx.x & 63;
    float4 v = *(const float4*)&h[(size_t)row * 256 + lane * 4];
    float sum = v.x + v.y + v.z + v.w;
    float sq  = v.x*v.x + v.y*v.y + v.z*v.z + v.w*v.w;
    #pragma unroll
    for (int off = 32; off > 0; off >>= 1) {
        sum += __shfl_xor(sum, off);
        sq  += __shfl_xor(sq, off);
    }
    float mu = sum * (1.f/256.f);
    float rs = rsqrtf(sq * (1.f/256.f) - mu*mu + 1e-5f);
    float4 wv = *(const float4*)&lw[lane*4];
    float4 bv = *(const float4*)&lb[lane*4];
    float o0 = (v.x-mu)*rs*wv.x + bv.x;
    float o1 = (v.y-mu)*rs*wv.y + bv.y;
    float o2 = (v.z-mu)*rs*wv.z + bv.z;
    float o3 = (v.w-mu)*rs*wv.w + bv.w;
    if (BFOUT) {
        *(ushort4*)((u16*)outp + (size_t)row*256 + lane*4) =
            make_ushort4(f2bf(o0), f2bf(o1), f2bf(o2), f2bf(o3));
    } else {
        *(float4*)((float*)outp + (size_t)row*256 + lane*4) = make_float4(o0,o1,o2,o3);
    }
}

// ---------- bf16 MFMA GEMM: C[M,n] = A[M,K] @ W[n,K]^T ----------
template<int KDIM, int MODE>
__global__ __launch_bounds__(256) void k_gemm(const u16* __restrict__ A,
        const u16* __restrict__ W, void* __restrict__ outp,
        const float* __restrict__ resptr, int ncols) {
    __shared__ u16 As[128*32];
    __shared__ u16 Bs[128*32];
    const int tid = threadIdx.x;
    const int wave = tid >> 6, lane = tid & 63;
    const int mbase = blockIdx.y * 128, nbase = blockIdx.x * 128;
    const int c0 = wave * 64 + lane;                 // staging chunk id (16B chunks)
    const u16* ga0 = A + (size_t)(mbase + (c0 >> 2)) * KDIM + (c0 & 3) * 8;
    const u16* ga1 = A + (size_t)(mbase + 64 + (c0 >> 2)) * KDIM + (c0 & 3) * 8;
    const u16* gb0 = W + (size_t)(nbase + (c0 >> 2)) * KDIM + (c0 & 3) * 8;
    const u16* gb1 = W + (size_t)(nbase + 64 + (c0 >> 2)) * KDIM + (c0 & 3) * 8;
    u16* la = As + wave * 512;
    u16* lb = Bs + wave * 512;
    f32x4 acc[4][4] = {};
    const int r0 = (wave & 1) * 64, cb = (wave >> 1) * 64;
    const int fr = lane & 15, kb = (lane >> 4) * 8;
    for (int k0 = 0; k0 < KDIM; k0 += 32) {
        gl_lds16(ga0 + k0, la);
        gl_lds16(ga1 + k0, la + 2048);
        gl_lds16(gb0 + k0, lb);
        gl_lds16(gb1 + k0, lb + 2048);
        __syncthreads();
        bf16x8 af[4], bq[4];
        #pragma unroll
        for (int m = 0; m < 4; m++)
            af[m] = *(const bf16x8*)&As[(r0 + m*16 + fr)*32 + kb];
        #pragma unroll
        for (int n = 0; n < 4; n++)
            bq[n] = *(const bf16x8*)&Bs[(cb + n*16 + fr)*32 + kb];
        #pragma unroll
        for (int m = 0; m < 4; m++)
            #pragma unroll
            for (int n = 0; n < 4; n++)
                acc[m][n] = __builtin_amdgcn_mfma_f32_16x16x32_bf16(af[m], bq[n], acc[m][n], 0, 0, 0);
        __syncthreads();
    }
    const int orow = mbase + r0 + (lane >> 4) * 4;
    const int ocol = nbase + cb + fr;
    if (MODE == 0) {
        u16* C = (u16*)outp;
        #pragma unroll
        for (int m = 0; m < 4; m++)
          #pragma unroll
          for (int n = 0; n < 4; n++)
            #pragma unroll
            for (int j = 0; j < 4; j++)
                C[(size_t)(orow + m*16 + j) * ncols + ocol + n*16] = f2bf(acc[m][n][j]);
    } else {
        float* H = (float*)outp;
        float res = resptr[0];
        #pragma unroll
        for (int m = 0; m < 4; m++)
          #pragma unroll
          for (int n = 0; n < 4; n++)
            #pragma unroll
            for (int j = 0; j < 4; j++) {
                size_t idx = (size_t)(orow + m*16 + j) * ncols + ocol + n*16;
                H[idx] += res * acc[m][n][j];
            }
    }
}

// ---------- depthwise causal conv4 + bias + SiLU; bf16 out ----------
__global__ __launch_bounds__(256) void k_conv(const u16* __restrict__ xz,
        const float* __restrict__ cw, const float* __restrict__ cb, u16* __restrict__ xs) {
    int b = blockIdx.x >> 5;
    int l0 = (blockIdx.x & 31) * 64 + (threadIdx.x >> 7) * 32;
    int c4 = (threadIdx.x & 127) * 4;
    float w[4][4], bias[4];
    #pragma unroll
    for (int j = 0; j < 4; j++) {
        float4 t = *(const float4*)&cw[(size_t)(c4 + j) * 4];
        w[j][0]=t.x; w[j][1]=t.y; w[j][2]=t.z; w[j][3]=t.w;
        bias[j] = cb[c4 + j];
    }
    size_t rowb = (size_t)b * LSEQ;
    float h0[4], h1[4], h2[4];
    #pragma unroll
    for (int j = 0; j < 4; j++) { h0[j]=0.f; h1[j]=0.f; h2[j]=0.f; }
    if (l0 >= 3) {
        ushort4 u;
        u = *(const ushort4*)&xz[(rowb + l0 - 3) * 1024 + c4];
        h0[0]=bf2f(u.x); h0[1]=bf2f(u.y); h0[2]=bf2f(u.z); h0[3]=bf2f(u.w);
        u = *(const ushort4*)&xz[(rowb + l0 - 2) * 1024 + c4];
        h1[0]=bf2f(u.x); h1[1]=bf2f(u.y); h1[2]=bf2f(u.z); h1[3]=bf2f(u.w);
        u = *(const ushort4*)&xz[(rowb + l0 - 1) * 1024 + c4];
        h2[0]=bf2f(u.x); h2[1]=bf2f(u.y); h2[2]=bf2f(u.z); h2[3]=bf2f(u.w);
    }
    for (int t = 0; t < 32; t++) {
        size_t row = rowb + l0 + t;
        ushort4 u = *(const ushort4*)&xz[row * 1024 + c4];
        float cur[4] = {bf2f(u.x), bf2f(u.y), bf2f(u.z), bf2f(u.w)};
        u16 ov[4];
        #pragma unroll
        for (int j = 0; j < 4; j++) {
            float v = w[j][0]*h0[j] + w[j][1]*h1[j] + w[j][2]*h2[j] + w[j][3]*cur[j] + bias[j];
            ov[j] = f2bf(v / (1.f + __expf(-v)));
        }
        *(ushort4*)&xs[row * 512 + c4] = make_ushort4(ov[0],ov[1],ov[2],ov[3]);
        #pragma unroll
        for (int j = 0; j < 4; j++) { h0[j]=h1[j]; h1[j]=h2[j]; h2[j]=cur[j]; }
    }
}

// ---------- x_proj: dbl[32768,48] = xs_bf16[32768,512] @ xw[48,512]^T ----------
__global__ __launch_bounds__(256) void k_xproj(const u16* __restrict__ xs,
        const float* __restrict__ xw, float* __restrict__ dbl) {
    __shared__ float sx[128][68];
    __shared__ float sw[48][68];
    int tid = threadIdx.x;
    int r0 = blockIdx.x * 128;
    int cg = tid & 3, rg = tid >> 2;
    float acc[2][12];
    #pragma unroll
    for (int r=0;r<2;r++)
        #pragma unroll
        for (int j=0;j<12;j++) acc[r][j]=0.f;
    for (int k0 = 0; k0 < 512; k0 += 64) {
        if (k0) __syncthreads();
        for (int i = tid; i < 2048; i += 256) {
            int rr = i >> 4, kk = (i & 15) * 4;
            ushort4 t4 = *(const ushort4*)&xs[(size_t)(r0+rr)*512 + k0 + kk];
            sx[rr][kk+0] = bf2f(t4.x); sx[rr][kk+1] = bf2f(t4.y);
            sx[rr][kk+2] = bf2f(t4.z); sx[rr][kk+3] = bf2f(t4.w);
        }
        for (int i = tid; i < 768; i += 256) {
            int rr = i >> 4, kk = (i & 15) * 4;
            *(float4*)&sw[rr][kk] = *(const float4*)&xw[(size_t)rr*512 + k0 + kk];
        }
        __syncthreads();
        #pragma unroll 4
        for (int k = 0; k < 64; k += 4) {
            float4 a0 = *(const float4*)&sx[rg*2][k];
            float4 a1 = *(const float4*)&sx[rg*2+1][k];
            #pragma unroll
            for (int j = 0; j < 12; j++) {
                float4 wv = *(const float4*)&sw[cg + 4*j][k];
                acc[0][j] += a0.x*wv.x + a0.y*wv.y + a0.z*wv.z + a0.w*wv.w;
                acc[1][j] += a1.x*wv.x + a1.y*wv.y + a1.z*wv.z + a1.w*wv.w;
            }
        }
    }
    #pragma unroll
    for (int r = 0; r < 2; r++)
        #pragma unroll
        for (int j = 0; j < 12; j++)
            dbl[(size_t)(r0 + rg*2 + r)*48 + cg + 4*j] = acc[r][j];
}

// ---------- selective scan: fused dt_proj+softplus, scan, Dp, SiLU(z) gate ----------
// block = 16 channels x 16 states; 32 blocks per batch elem.
__global__ __launch_bounds__(256) void k_scan(
        const u16* __restrict__ xs, const float* __restrict__ dbl,
        const u16* __restrict__ xz, const float* __restrict__ A_log,
        const float* __restrict__ Dp, const float* __restrict__ dtw,
        const float* __restrict__ dtb, u16* __restrict__ y2) {
    __shared__ float sdtT[16][68];   // [c][t]
    __shared__ float sxsT[16][68];   // [c][t]
    __shared__ float sBT[16][68];    // [s][t]
    __shared__ float sCT[16][68];    // [s][t]
    __shared__ float sdl[64][20];    // [t][k] dt_low (pad 20 keeps b128 align + banks spread)
    __shared__ u16   sz[64][16];     // [t][c]
    __shared__ float sy[64][16];     // [t][c] pre-gate y
    const int b = blockIdx.x >> 5;
    const int cbase = (blockIdx.x & 31) * 16;
    const int tid = threadIdx.x;
    const int cl = tid >> 4, s = tid & 15;
    const float A = -__expf(A_log[(size_t)(cbase + cl) * 16 + s]);
    const float dp = Dp[cbase + cl];
    // dt-proj weights for this thread's 4 channels (dt-compute mapping)
    const int dtt = tid >> 2;        // t index this thread computes dt for
    const int dc0 = (tid & 3) * 4;   // first of its 4 channels
    f32x4 wreg[4][4];
    float breg[4];
    #pragma unroll
    for (int q = 0; q < 4; q++) {
        #pragma unroll
        for (int m = 0; m < 4; m++)
            wreg[q][m] = *(const f32x4*)&dtw[(size_t)(cbase + dc0 + q) * 16 + 4*m];
        breg[q] = dtb[cbase + dc0 + q];
    }
    float h = 0.f;
    const size_t rowb = (size_t)b * LSEQ;
    for (int t0 = 0; t0 < LSEQ; t0 += 64) {
        for (int i = tid; i < 1024; i += 256) {
            const int tt = i >> 4, j = i & 15;
            const size_t row = rowb + t0 + tt;
            const float* dptr = &dbl[row * 48];
            sdl[tt][j]  = dptr[j];
            sBT[j][tt]  = dptr[16 + j];
            sCT[j][tt]  = dptr[32 + j];
            sxsT[j][tt] = bf2f(xs[row * 512 + cbase + j]);
            sz[tt][j]   = xz[row * 1024 + 512 + cbase + j];
        }
        __syncthreads();
        {   // dt = softplus(bias + dt_low @ w^T): 4 (t,c) entries per thread
            float a0 = breg[0], a1 = breg[1], a2 = breg[2], a3 = breg[3];
            #pragma unroll
            for (int m = 0; m < 4; m++) {
                const f32x4 xv4 = *(const f32x4*)&sdl[dtt][4*m];
                #pragma unroll
                for (int e = 0; e < 4; e++) {
                    a0 = fmaf(xv4[e], wreg[0][m][e], a0);
                    a1 = fmaf(xv4[e], wreg[1][m][e], a1);
                    a2 = fmaf(xv4[e], wreg[2][m][e], a2);
                    a3 = fmaf(xv4[e], wreg[3][m][e], a3);
                }
            }
            sdtT[dc0+0][dtt] = (a0 > 15.f) ? a0 : log1pf(__expf(a0));
            sdtT[dc0+1][dtt] = (a1 > 15.f) ? a1 : log1pf(__expf(a1));
            sdtT[dc0+2][dtt] = (a2 > 15.f) ? a2 : log1pf(__expf(a2));
            sdtT[dc0+3][dtt] = (a3 > 15.f) ? a3 : log1pf(__expf(a3));
        }
        __syncthreads();
        for (int tq = 0; tq < 64; tq += 4) {
            const f32x4 dtq = *(const f32x4*)&sdtT[cl][tq];
            const f32x4 xq  = *(const f32x4*)&sxsT[cl][tq];
            const f32x4 bq  = *(const f32x4*)&sBT[s][tq];
            const f32x4 cq  = *(const f32x4*)&sCT[s][tq];
            #pragma unroll
            for (int u = 0; u < 4; u++) {
                const float dtv = dtq[u];
                const float dA = __expf(dtv * A);
                h = h * dA + dtv * xq[u] * bq[u];
                float p = row_reduce16(h * cq[u]);
                if (s == 0) sy[tq + u][cl] = p + xq[u] * dp;
            }
        }
        __syncthreads();
        for (int i = tid; i < 1024; i += 256) {
            const int tt = i >> 4, j = i & 15;
            const float zf = bf2f(sz[tt][j]);
            const float g = zf / (1.f + __expf(-zf));
            y2[(rowb + t0 + tt) * 512 + cbase + j] = f2bf(sy[tt][j] * g);
        }
        __syncthreads();
    }
}

extern "C" void kernel_launch(void* const* d_in, const int* in_sizes, int n_in,
                              void* d_out, int out_size, void* d_ws, size_t ws_size,
                              hipStream_t stream) {
    const float* seq       = (const float*)d_in[0];
    const float* inp_w     = (const float*)d_in[1];
    const float* inp_b     = (const float*)d_in[2];
    const float* ln_w      = (const float*)d_in[3];
    const float* ln_b      = (const float*)d_in[4];
    const float* in_proj_w = (const float*)d_in[5];
    const float* conv_w    = (const float*)d_in[6];
    const float* conv_b    = (const float*)d_in[7];
    const float* x_proj_w  = (const float*)d_in[8];
    const float* dt_proj_w = (const float*)d_in[9];
    const float* dt_proj_b = (const float*)d_in[10];
    const float* A_log     = (const float*)d_in[11];
    const float* Dp        = (const float*)d_in[12];
    const float* out_proj_w= (const float*)d_in[13];
    const float* res_scale = (const float*)d_in[14];
    const float* out_ln_w  = (const float*)d_in[15];
    const float* out_ln_b  = (const float*)d_in[16];

    // workspace: 193.2 MB total (was 293.8 MB -> suspected d_ws overrun fault)
    char* ws = (char*)d_ws;
    float* f_h    = (float*)ws;  ws += (size_t)NROWS*256*4;   // 33.5 MB
    u16*   bf_xn  = (u16*)ws;    ws += (size_t)NROWS*256*2;   // 16.8 MB
    u16*   bf_w1  = (u16*)ws;    ws += (size_t)3*1024*256*2;  //  1.6 MB
    u16*   bf_w2  = (u16*)ws;    ws += (size_t)3*256*512*2;   //  0.8 MB
    u16*   bf_xz  = (u16*)ws;    ws += (size_t)NROWS*1024*2;  // 67.1 MB
    u16*   bf_xs  = (u16*)ws;    ws += (size_t)NROWS*512*2;   // 33.5 MB
    float* f_dbl  = (float*)ws;  ws += (size_t)NROWS*48*4;    //  6.3 MB
    u16*   bf_y2  = (u16*)ws;    ws += (size_t)NROWS*512*2;   // 33.5 MB

    k_tobf16<<<(3*1024*256 + 255)/256, 256, 0, stream>>>(in_proj_w, bf_w1, 3*1024*256);
    k_tobf16<<<(3*256*512 + 255)/256, 256, 0, stream>>>(out_proj_w, bf_w2, 3*256*512);
    k_embed<<<NROWS/8, 256, 0, stream>>>(seq, inp_w, inp_b, f_h);

    for (int l = 0; l < 3; l++) {
        k_ln<true><<<NROWS/4, 256, 0, stream>>>(f_h, ln_w + l*256, ln_b + l*256, (void*)bf_xn);
        k_gemm<256,0><<<dim3(8, NROWS/128), 256, 0, stream>>>(bf_xn, bf_w1 + (size_t)l*1024*256,
                                                              (void*)bf_xz, nullptr, 1024);
        k_conv<<<512, 256, 0, stream>>>(bf_xz, conv_w + (size_t)l*512*4, conv_b + (size_t)l*512, bf_xs);
        k_xproj<<<NROWS/128, 256, 0, stream>>>(bf_xs, x_proj_w + (size_t)l*48*512, f_dbl);
        k_scan<<<512, 256, 0, stream>>>(bf_xs, f_dbl, bf_xz,
                                        A_log + (size_t)l*512*16, Dp + (size_t)l*512,
                                        dt_proj_w + (size_t)l*512*16, dt_proj_b + (size_t)l*512,
                                        bf_y2);
        k_gemm<512,1><<<dim3(2, NROWS/128), 256, 0, stream>>>(bf_y2, bf_w2 + (size_t)l*256*512,
                                                              (void*)f_h, res_scale + l, 256);
    }
    k_ln<false><<<NROWS/4, 256, 0, stream>>>(f_h, out_ln_w, out_ln_b, d_out);
}